// Round 3
// baseline (339.556 us; speedup 1.0000x reference)
//
#include <hip/hip_runtime.h>
#include <hip/hip_bf16.h>

#define D 128

typedef __bf16 bf16x8 __attribute__((ext_vector_type(8)));
typedef __bf16 bf16x4 __attribute__((ext_vector_type(4)));
typedef __bf16 bf16x2 __attribute__((ext_vector_type(2)));
typedef float  f32x4  __attribute__((ext_vector_type(4)));
typedef float  f32x2  __attribute__((ext_vector_type(2)));
typedef unsigned int u32x4 __attribute__((ext_vector_type(4)));

// ---------------------------------------------------------------------------
// Dtype probe: 1 = bf16-packed, 0 = fp32 (R3-R6 evidence: bf16).
// ---------------------------------------------------------------------------
__global__ void detect_kernel(const unsigned int* __restrict__ w, int* flag)
{
    __shared__ int cnt[256];
    int c = 0;
#pragma unroll
    for (int i = 0; i < 4; ++i) {
        unsigned int v = w[threadIdx.x * 4 + i];
        unsigned int e = (v >> 7) & 0xFF;
        if (e >= 90 && e <= 134) ++c;
    }
    cnt[threadIdx.x] = c;
    __syncthreads();
    for (int s = 128; s > 0; s >>= 1) {
        if (threadIdx.x < s) cnt[threadIdx.x] += cnt[threadIdx.x + s];
        __syncthreads();
    }
    if (threadIdx.x == 0) flag[0] = (cnt[0] > 614) ? 1 : 0;
}

template <int ISBF>
__device__ __forceinline__ bf16x8 ld8(const void* p, size_t elem)
{
    if (ISBF) return *(const bf16x8*)((const __bf16*)p + elem);
    const f32x4* f = (const f32x4*)((const float*)p + elem);
    f32x4 lo = f[0], hi = f[1];
    bf16x8 r;
    r[0] = (__bf16)lo[0]; r[1] = (__bf16)lo[1]; r[2] = (__bf16)lo[2]; r[3] = (__bf16)lo[3];
    r[4] = (__bf16)hi[0]; r[5] = (__bf16)hi[1]; r[6] = (__bf16)hi[2]; r[7] = (__bf16)hi[3];
    return r;
}
template <int ISBF>
__device__ __forceinline__ float ldf(const void* p, size_t elem)
{
    return ISBF ? (float)((const __bf16*)p)[elem] : ((const float*)p)[elem];
}

// bf16 pair (packed in one u32) -> f32x2 via bit ops (no cvt chain)
__device__ __forceinline__ f32x2 bfpair(unsigned int u)
{
    f32x2 r;
    r[0] = __builtin_bit_cast(float, u << 16);
    r[1] = __builtin_bit_cast(float, u & 0xffff0000u);
    return r;
}

// packed f32 fma: d = a*b + c (VOP3P v_pk_fma_f32, gfx90a+)
__device__ __forceinline__ f32x2 pkfma(f32x2 a, f32x2 b, f32x2 c)
{
    f32x2 d;
    asm("v_pk_fma_f32 %0, %1, %2, %3" : "=v"(d) : "v"(a), "v"(b), "v"(c));
    return d;
}

// ---------------------------------------------------------------------------
// Gate pre-activations G[t][n]: 16 lanes per node, 16B loads, 4-step shfl.
// ---------------------------------------------------------------------------
template <int ISBF>
__device__ __forceinline__ void gate_body(
    const void* __restrict__ A,
    const void* __restrict__ g0, const void* __restrict__ g1,
    const void* __restrict__ g2, const void* __restrict__ g3,
    float* __restrict__ G, int M)
{
    int node = blockIdx.x * 16 + (threadIdx.x >> 4);
    if (node >= M) return;
    int lane16 = threadIdx.x & 15;
    int dd = lane16 * 8;
    bf16x8 a  = ld8<ISBF>(A, (size_t)node * D + dd);
    bf16x8 q0 = ld8<ISBF>(g0, dd);
    bf16x8 q1 = ld8<ISBF>(g1, dd);
    bf16x8 q2 = ld8<ISBF>(g2, dd);
    bf16x8 q3 = ld8<ISBF>(g3, dd);
    float s0 = 0.f, s1 = 0.f, s2 = 0.f, s3 = 0.f;
#pragma unroll
    for (int k = 0; k < 8; ++k) {
        float af = (float)a[k];
        s0 = fmaf(af, (float)q0[k], s0);
        s1 = fmaf(af, (float)q1[k], s1);
        s2 = fmaf(af, (float)q2[k], s2);
        s3 = fmaf(af, (float)q3[k], s3);
    }
#pragma unroll
    for (int off = 8; off > 0; off >>= 1) {
        s0 += __shfl_xor(s0, off);
        s1 += __shfl_xor(s1, off);
        s2 += __shfl_xor(s2, off);
        s3 += __shfl_xor(s3, off);
    }
    if (lane16 == 0) {
        G[(size_t)0 * M + node] = s0;
        G[(size_t)1 * M + node] = s1;
        G[(size_t)2 * M + node] = s2;
        G[(size_t)3 * M + node] = s3;
    }
}

__global__ __launch_bounds__(256) void gate_kernel(
    const void* __restrict__ A,
    const void* __restrict__ g0, const void* __restrict__ g1,
    const void* __restrict__ g2, const void* __restrict__ g3,
    float* __restrict__ G, int M, const int* __restrict__ flag)
{
    if (flag[0]) gate_body<1>(A, g0, g1, g2, g3, G, M);
    else         gate_body<0>(A, g0, g1, g2, g3, G, M);
}

// ---------------------------------------------------------------------------
// Combined zero-padded bias tables:
//   Bz [101][128] bf16 : rows 0..49 = b_in, 50..99 = b_out, 100 = zeros
//   Bgz[101]      f32  : same layout for gate biases
// ---------------------------------------------------------------------------
__global__ __launch_bounds__(128) void build_bias_kernel(
    const void* __restrict__ b_in, const void* __restrict__ b_out,
    const void* __restrict__ bg_in, const void* __restrict__ bg_out,
    __bf16* __restrict__ Bz, float* __restrict__ Bgz,
    const int* __restrict__ flag)
{
    int row = blockIdx.x;       // 0..100
    int tid = threadIdx.x;      // 0..127
    int isbf = flag[0];
    float v = 0.f, gv = 0.f;
    if (row < 50) {
        v  = isbf ? ldf<1>(b_in, (size_t)row * D + tid) : ldf<0>(b_in, (size_t)row * D + tid);
        gv = isbf ? ldf<1>(bg_in, row) : ldf<0>(bg_in, row);
    } else if (row < 100) {
        int rr = row - 50;
        v  = isbf ? ldf<1>(b_out, (size_t)rr * D + tid) : ldf<0>(b_out, (size_t)rr * D + tid);
        gv = isbf ? ldf<1>(bg_out, rr) : ldf<0>(bg_out, rr);
    }
    Bz[(size_t)row * D + tid] = (__bf16)v;
    if (tid == 0) Bgz[row] = gv;
}

// ---------------------------------------------------------------------------
// CSR build (verified R4-R6)
// ---------------------------------------------------------------------------
__global__ __launch_bounds__(256) void hist_kernel(
    const int* __restrict__ tgt, int* __restrict__ counts, int E)
{
    int e = blockIdx.x * 256 + threadIdx.x;
    if (e < E) atomicAdd(&counts[tgt[e]], 1);
}

__global__ __launch_bounds__(256) void scan1_kernel(
    const int* __restrict__ counts, int* __restrict__ rowptr,
    int* __restrict__ bsum, int M)
{
    __shared__ int sh[256];
    int base = blockIdx.x * 1024 + threadIdx.x * 4;
    int v[4];
#pragma unroll
    for (int k = 0; k < 4; ++k)
        v[k] = (base + k < M) ? counts[base + k] : 0;
    int tot = v[0] + v[1] + v[2] + v[3];
    sh[threadIdx.x] = tot;
    __syncthreads();
    for (int off = 1; off < 256; off <<= 1) {
        int t = (threadIdx.x >= off) ? sh[threadIdx.x - off] : 0;
        __syncthreads();
        sh[threadIdx.x] += t;
        __syncthreads();
    }
    int run = sh[threadIdx.x] - tot;
#pragma unroll
    for (int k = 0; k < 4; ++k) {
        if (base + k < M) rowptr[base + k] = run;
        run += v[k];
    }
    if (threadIdx.x == 255) bsum[blockIdx.x] = sh[255];
}

__global__ __launch_bounds__(256) void scan2_kernel(
    int* __restrict__ bsum, int* __restrict__ boff, int NB)
{
    __shared__ int sh[256];
    int base = threadIdx.x * 4;
    int v[4];
#pragma unroll
    for (int k = 0; k < 4; ++k)
        v[k] = (base + k < NB) ? bsum[base + k] : 0;
    int tot = v[0] + v[1] + v[2] + v[3];
    sh[threadIdx.x] = tot;
    __syncthreads();
    for (int off = 1; off < 256; off <<= 1) {
        int t = (threadIdx.x >= off) ? sh[threadIdx.x - off] : 0;
        __syncthreads();
        sh[threadIdx.x] += t;
        __syncthreads();
    }
    int run = sh[threadIdx.x] - tot;
#pragma unroll
    for (int k = 0; k < 4; ++k) {
        if (base + k < NB) boff[base + k] = run;
        run += v[k];
    }
}

__global__ __launch_bounds__(256) void scan3_kernel(
    int* __restrict__ rowptr, int* __restrict__ cursor,
    const int* __restrict__ boff, int M, int E)
{
    int b = blockIdx.x;
    int base = b * 1024 + threadIdx.x * 4;
    int o = boff[b];
#pragma unroll
    for (int k = 0; k < 4; ++k) {
        int i = base + k;
        if (i < M) {
            int r = rowptr[i] + o;
            rowptr[i] = r;
            cursor[i] = r;
        }
    }
    if (b == 0 && threadIdx.x == 0) rowptr[M] = E;
}

__global__ __launch_bounds__(256) void scatter_kernel(
    const int* __restrict__ deprel, const int* __restrict__ deparc,
    const int* __restrict__ src, const int* __restrict__ tgt,
    int* __restrict__ cursor, int2* __restrict__ recs, int E)
{
    int e = blockIdx.x * 256 + threadIdx.x;
    if (e >= E) return;
    int g = tgt[e];
    int pos = atomicAdd(&cursor[g], 1);
    recs[pos] = make_int2(src[e], (deprel[e] << 2) | deparc[e]);
}

// ---------------------------------------------------------------------------
// Degree-sort: counting sort of nodes into 64 degree bins -> perm.
// Groups within a wave then process near-equal-degree nodes (balance).
// ---------------------------------------------------------------------------
__global__ __launch_bounds__(256) void deg_hist_kernel(
    const int* __restrict__ counts, int* __restrict__ dcnt, int M)
{
    __shared__ int lh[64];
    if (threadIdx.x < 64) lh[threadIdx.x] = 0;
    __syncthreads();
    int i = blockIdx.x * 256 + threadIdx.x;
    if (i < M) {
        int d = counts[i]; if (d > 63) d = 63;
        atomicAdd(&lh[d], 1);
    }
    __syncthreads();
    if (threadIdx.x < 64 && lh[threadIdx.x])
        atomicAdd(&dcnt[threadIdx.x], lh[threadIdx.x]);
}

__global__ void deg_scan_kernel(const int* __restrict__ dcnt, int* __restrict__ dcur)
{
    if (threadIdx.x == 0) {
        int run = 0;
        for (int i = 0; i < 64; ++i) { dcur[i] = run; run += dcnt[i]; }
    }
}

__global__ __launch_bounds__(256) void deg_scatter_kernel(
    const int* __restrict__ counts, int* __restrict__ dcur,
    int* __restrict__ perm, int M)
{
    __shared__ int lh[64];
    __shared__ int gb[64];
    if (threadIdx.x < 64) lh[threadIdx.x] = 0;
    __syncthreads();
    int i = blockIdx.x * 256 + threadIdx.x;
    int d = 0, lpos = 0;
    if (i < M) {
        d = counts[i]; if (d > 63) d = 63;
        lpos = atomicAdd(&lh[d], 1);
    }
    __syncthreads();
    if (threadIdx.x < 64 && lh[threadIdx.x])
        gb[threadIdx.x] = atomicAdd(&dcur[threadIdx.x], lh[threadIdx.x]);
    __syncthreads();
    if (i < M) perm[gb[d] + lpos] = i;
}

// ---------------------------------------------------------------------------
// Phase A v3: 16 lanes/node over degree-sorted perm; 3-deep pipeline;
// packed-f32 FMA accumulation; branchless via zero-padded bias table.
// ---------------------------------------------------------------------------
template <int ISBF>
__device__ __forceinline__ void edge_agg_body(
    const void* __restrict__ inp, const float* __restrict__ G,
    const __bf16* __restrict__ Bz, const float* __restrict__ Bgz,
    const int* __restrict__ rowptr, const int2* __restrict__ recs,
    const int* __restrict__ perm,
    __bf16* __restrict__ AG, __bf16* __restrict__ BA, int M)
{
    const int idx = blockIdx.x * 16 + (threadIdx.x >> 4);
    if (idx >= M) return;
    const int g = perm[idx];
    const int lane16 = threadIdx.x & 15;
    const int dd = lane16 * 8;

    const int beg = rowptr[g], end = rowptr[g + 1];
    const int n = end - beg;

    f32x2 a0[4], a1[4], a2[4], a3[4], ba[4];
#pragma unroll
    for (int k = 0; k < 4; ++k) {
        a0[k] = (f32x2){0.f, 0.f}; a1[k] = (f32x2){0.f, 0.f};
        a2[k] = (f32x2){0.f, 0.f}; a3[k] = (f32x2){0.f, 0.f};
        ba[k] = (f32x2){0.f, 0.f};
    }

    // pipeline stages
    bf16x8 v0 = {}, bz0 = {}, v1 = {}, bz1 = {};
    float gp0 = 0.f, bg0 = 0.f, gp1 = 0.f, bg1 = 0.f;
    int t0 = 0, t1 = 0;
    int2 r2 = make_int2(0, 0);

    auto issue = [&](int2 rec, bf16x8& v, bf16x8& bz, float& gp, float& bg, int& t) {
        t = rec.y & 3;
        int r = rec.y >> 2;
        int bidx = (t < 2) ? t * 50 + r : 100;
        gp = G[(size_t)t * M + rec.x];
        bg = Bgz[bidx];
        v  = ld8<ISBF>(inp, (size_t)rec.x * D + dd);
        bz = *(const bf16x8*)(Bz + (size_t)bidx * D + dd);
    };

    if (n > 0) issue(recs[beg], v0, bz0, gp0, bg0, t0);
    if (n > 1) issue(recs[beg + 1], v1, bz1, gp1, bg1, t1);
    if (n > 2) r2 = recs[beg + 2];

    for (int e = 0; e < n; ++e) {
        const bf16x8 v = v0, bz = bz0;
        const float gp = gp0, bg = bg0;
        const int t = t0;

        // shift + issue next
        v0 = v1; bz0 = bz1; gp0 = gp1; bg0 = bg1; t0 = t1;
        if (e + 2 < n) {
            issue(r2, v1, bz1, gp1, bg1, t1);
            if (e + 3 < n) r2 = recs[beg + e + 3];
        }

        const float gate = 1.f / (1.f + __expf(-(gp + bg)));
        const float w0s = (t == 0) ? gate : 0.f;
        const float w1s = (t == 1) ? gate : 0.f;
        const float w2s = (t == 2) ? gate : 0.f;
        const float w3s = (t == 3) ? gate : 0.f;
        const f32x2 w0 = {w0s, w0s}, w1 = {w1s, w1s};
        const f32x2 w2 = {w2s, w2s}, w3 = {w3s, w3s};
        const f32x2 gg = {gate, gate};

        const u32x4 uv = __builtin_bit_cast(u32x4, v);
        const u32x4 ub = __builtin_bit_cast(u32x4, bz);
#pragma unroll
        for (int k = 0; k < 4; ++k) {
            const f32x2 vf = bfpair(uv[k]);
            const f32x2 bf = bfpair(ub[k]);
            a0[k] = pkfma(vf, w0, a0[k]);
            a1[k] = pkfma(vf, w1, a1[k]);
            a2[k] = pkfma(vf, w2, a2[k]);
            a3[k] = pkfma(vf, w3, a3[k]);
            ba[k] = pkfma(bf, gg, ba[k]);
        }
    }

    // epilogue: direct stores
    __bf16* agrow = AG + (size_t)g * (4 * D);
    bf16x8 w;
#pragma unroll
    for (int k = 0; k < 4; ++k) { w[2*k] = (__bf16)a0[k][0]; w[2*k+1] = (__bf16)a0[k][1]; }
    *(bf16x8*)(agrow + 0 * D + dd) = w;
#pragma unroll
    for (int k = 0; k < 4; ++k) { w[2*k] = (__bf16)a1[k][0]; w[2*k+1] = (__bf16)a1[k][1]; }
    *(bf16x8*)(agrow + 1 * D + dd) = w;
#pragma unroll
    for (int k = 0; k < 4; ++k) { w[2*k] = (__bf16)a2[k][0]; w[2*k+1] = (__bf16)a2[k][1]; }
    *(bf16x8*)(agrow + 2 * D + dd) = w;
#pragma unroll
    for (int k = 0; k < 4; ++k) { w[2*k] = (__bf16)a3[k][0]; w[2*k+1] = (__bf16)a3[k][1]; }
    *(bf16x8*)(agrow + 3 * D + dd) = w;
#pragma unroll
    for (int k = 0; k < 4; ++k) { w[2*k] = (__bf16)ba[k][0]; w[2*k+1] = (__bf16)ba[k][1]; }
    *(bf16x8*)(BA + (size_t)g * D + dd) = w;
}

__global__ __launch_bounds__(256) void edge_agg_kernel(
    const void* __restrict__ inp, const float* __restrict__ G,
    const __bf16* __restrict__ Bz, const float* __restrict__ Bgz,
    const int* __restrict__ rowptr, const int2* __restrict__ recs,
    const int* __restrict__ perm,
    __bf16* __restrict__ AG, __bf16* __restrict__ BA, int M,
    const int* __restrict__ flag)
{
    if (flag[0]) edge_agg_body<1>(inp, G, Bz, Bgz, rowptr, recs, perm, AG, BA, M);
    else         edge_agg_body<0>(inp, G, Bz, Bgz, rowptr, recs, perm, AG, BA, M);
}

// ---------------------------------------------------------------------------
// Phase B: out = AG[M,512] @ WW^T + BA, W staged in LDS (XOR-swizzled).
// ---------------------------------------------------------------------------
template <int ISBF>
__device__ __forceinline__ void gemm2_body(
    const __bf16* __restrict__ AG, const __bf16* __restrict__ BA,
    const void* __restrict__ W0, const void* __restrict__ W1,
    const void* __restrict__ W2, const void* __restrict__ W3,
    void* __restrict__ out, int M)
{
    __shared__ __bf16 Wsh[128 * 128];   // 32 KB, row f: 16 slots of 16B, swizzled

    const int wave = threadIdx.x >> 6;
    const int lane = threadIdx.x & 63;
    const int lrow = lane & 15;
    const int kgrp = lane >> 4;
    const int m_base = blockIdx.x * 128 + wave * 32;

    int n0 = m_base + lrow;      if (n0 >= M) n0 = 0;   // clamped; stores guarded
    int n1 = m_base + 16 + lrow; if (n1 >= M) n1 = 0;

    const void* Ws[4] = {W0, W1, W2, W3};

    f32x4 acc[2][8];
#pragma unroll
    for (int i = 0; i < 2; ++i)
#pragma unroll
        for (int j = 0; j < 8; ++j)
            acc[i][j] = (f32x4){0.f, 0.f, 0.f, 0.f};

    for (int t = 0; t < 4; ++t) {
        const void* W = Ws[t];
#pragma unroll
        for (int i = 0; i < 8; ++i) {
            int slot = threadIdx.x + 256 * i;
            int f = slot >> 4;
            int s = slot & 15;
            int sp = s ^ (f & 7);
            bf16x8 v = ld8<ISBF>(W, (size_t)f * D + s * 8);
            *(bf16x8*)(Wsh + f * 128 + sp * 8) = v;
        }
        __syncthreads();

#pragma unroll
        for (int ks = 0; ks < 4; ++ks) {
            const int k0 = ks * 32 + kgrp * 8;                 // k within t
            bf16x8 af0 = *(const bf16x8*)(AG + (size_t)n0 * (4 * D) + t * D + k0);
            bf16x8 af1 = *(const bf16x8*)(AG + (size_t)n1 * (4 * D) + t * D + k0);
            const int slot = 4 * ks + kgrp;                    // 16B slot index
#pragma unroll
            for (int ft = 0; ft < 8; ++ft) {
                int f = ft * 16 + lrow;
                int sp = slot ^ (f & 7);
                bf16x8 wf = *(const bf16x8*)(Wsh + f * 128 + sp * 8);
                acc[0][ft] = __builtin_amdgcn_mfma_f32_16x16x32_bf16(wf, af0, acc[0][ft], 0, 0, 0);
                acc[1][ft] = __builtin_amdgcn_mfma_f32_16x16x32_bf16(wf, af1, acc[1][ft], 0, 0, 0);
            }
        }
        __syncthreads();
    }

    // epilogue (layout verified R5/R6): node = col, features = kgrp*4+reg +ft*16
#pragma unroll
    for (int nt = 0; nt < 2; ++nt) {
        int node = m_base + nt * 16 + lrow;
        if (node < M) {
#pragma unroll
            for (int ft = 0; ft < 8; ++ft) {
                int f0 = ft * 16 + kgrp * 4;
                bf16x4 bb = *(const bf16x4*)(BA + (size_t)node * D + f0);
                f32x4 v = acc[nt][ft];
                v[0] += (float)bb[0]; v[1] += (float)bb[1];
                v[2] += (float)bb[2]; v[3] += (float)bb[3];
                if (ISBF) {
                    bf16x4 w4;
                    w4[0] = (__bf16)v[0]; w4[1] = (__bf16)v[1];
                    w4[2] = (__bf16)v[2]; w4[3] = (__bf16)v[3];
                    *(bf16x4*)((__bf16*)out + (size_t)node * D + f0) = w4;
                } else {
                    *(f32x4*)((float*)out + (size_t)node * D + f0) = v;
                }
            }
        }
    }
}

__global__ __launch_bounds__(256) void gemm2_kernel(
    const __bf16* __restrict__ AG, const __bf16* __restrict__ BA,
    const void* __restrict__ W0, const void* __restrict__ W1,
    const void* __restrict__ W2, const void* __restrict__ W3,
    void* __restrict__ out, int M, const int* __restrict__ flag)
{
    if (flag[0]) gemm2_body<1>(AG, BA, W0, W1, W2, W3, out, M);
    else         gemm2_body<0>(AG, BA, W0, W1, W2, W3, out, M);
}

__global__ void sentinel_kernel(__bf16* o, int n)
{
    int i = blockIdx.x * blockDim.x + threadIdx.x;
    if (i < n) o[i] = (__bf16)12345.0f;
}

static inline size_t align256(size_t x) { return (x + 255) & ~(size_t)255; }

extern "C" void kernel_launch(void* const* d_in, const int* in_sizes, int n_in,
                              void* d_out, int out_size, void* d_ws, size_t ws_size,
                              hipStream_t stream)
{
    const void* inp       = d_in[0];
    const int*  deprel    = (const int*)d_in[1];
    const int*  deparc    = (const int*)d_in[2];
    const int*  eidx      = (const int*)d_in[3];
    const void* V_in      = d_in[4];
    const void* b_in      = d_in[5];
    const void* V_in_g    = d_in[6];
    const void* b_in_g    = d_in[7];
    const void* V_out     = d_in[8];
    const void* b_out     = d_in[9];
    const void* V_out_g   = d_in[10];
    const void* b_out_g   = d_in[11];
    const void* W_self    = d_in[12];
    const void* W_self_g  = d_in[13];
    const void* W_norel   = d_in[14];
    const void* W_norel_g = d_in[15];

    const int M = in_sizes[0] / D;   // 100000
    const int E = in_sizes[1];       // 600000
    const int* src = eidx;
    const int* tgt = eidx + E;
    const int NB = (M + 1023) / 1024;

    size_t off = 0;
    size_t o_flag   = off; off = align256(off + sizeof(int));
    size_t o_AG     = off; off = align256(off + (size_t)M * 4 * D * sizeof(__bf16));
    size_t o_BA     = off; off = align256(off + (size_t)M * D * sizeof(__bf16));
    size_t o_G      = off; off = align256(off + (size_t)4 * M * sizeof(float));
    size_t o_counts = off; off = align256(off + (size_t)M * sizeof(int));
    size_t o_rowptr = off; off = align256(off + (size_t)(M + 1) * sizeof(int));
    size_t o_cursor = off; off = align256(off + (size_t)M * sizeof(int));
    size_t o_bsum   = off; off = align256(off + (size_t)NB * sizeof(int));
    size_t o_boff   = off; off = align256(off + (size_t)NB * sizeof(int));
    size_t o_recs   = off; off = align256(off + (size_t)E * sizeof(int2));
    size_t o_Bz     = off; off = align256(off + (size_t)101 * D * sizeof(__bf16));
    size_t o_Bgz    = off; off = align256(off + (size_t)101 * sizeof(float));
    size_t o_perm   = off; off = align256(off + (size_t)M * sizeof(int));
    size_t o_dcnt   = off; off = align256(off + (size_t)64 * sizeof(int));
    size_t o_dcur   = off; off = align256(off + (size_t)64 * sizeof(int));

    if (off > ws_size) {
        sentinel_kernel<<<(out_size + 255) / 256, 256, 0, stream>>>(
            (__bf16*)d_out, out_size);
        return;
    }

    int*    flag   = (int*)((char*)d_ws + o_flag);
    __bf16* AG     = (__bf16*)((char*)d_ws + o_AG);
    __bf16* BA     = (__bf16*)((char*)d_ws + o_BA);
    float*  Gbuf   = (float*)((char*)d_ws + o_G);
    int*    counts = (int*)((char*)d_ws + o_counts);
    int*    rowptr = (int*)((char*)d_ws + o_rowptr);
    int*    cursor = (int*)((char*)d_ws + o_cursor);
    int*    bsum   = (int*)((char*)d_ws + o_bsum);
    int*    boff   = (int*)((char*)d_ws + o_boff);
    int2*   recs   = (int2*)((char*)d_ws + o_recs);
    __bf16* Bz     = (__bf16*)((char*)d_ws + o_Bz);
    float*  Bgz    = (float*)((char*)d_ws + o_Bgz);
    int*    perm   = (int*)((char*)d_ws + o_perm);
    int*    dcnt   = (int*)((char*)d_ws + o_dcnt);
    int*    dcur   = (int*)((char*)d_ws + o_dcur);

    detect_kernel<<<1, 256, 0, stream>>>((const unsigned int*)inp, flag);

    // CSR build
    hipMemsetAsync(counts, 0, (size_t)M * sizeof(int), stream);
    hipMemsetAsync(dcnt, 0, 64 * sizeof(int), stream);
    hist_kernel<<<(E + 255) / 256, 256, 0, stream>>>(tgt, counts, E);

    // degree-sorted node permutation (counting sort, 64 bins)
    deg_hist_kernel<<<(M + 255) / 256, 256, 0, stream>>>(counts, dcnt, M);
    deg_scan_kernel<<<1, 64, 0, stream>>>(dcnt, dcur);
    deg_scatter_kernel<<<(M + 255) / 256, 256, 0, stream>>>(counts, dcur, perm, M);

    scan1_kernel<<<NB, 256, 0, stream>>>(counts, rowptr, bsum, M);
    scan2_kernel<<<1, 256, 0, stream>>>(bsum, boff, NB);
    scan3_kernel<<<NB, 256, 0, stream>>>(rowptr, cursor, boff, M, E);
    scatter_kernel<<<(E + 255) / 256, 256, 0, stream>>>(deprel, deparc, src, tgt,
                                                        cursor, recs, E);

    // bias tables + gates
    build_bias_kernel<<<101, 128, 0, stream>>>(b_in, b_out, b_in_g, b_out_g,
                                               Bz, Bgz, flag);
    gate_kernel<<<(M + 15) / 16, 256, 0, stream>>>(inp, V_in_g, V_out_g, W_self_g,
                                                   W_norel_g, Gbuf, M, flag);

    // aggregate-then-transform
    edge_agg_kernel<<<(M + 15) / 16, 256, 0, stream>>>(inp, Gbuf, Bz, Bgz,
                                                       rowptr, recs, perm,
                                                       AG, BA, M, flag);
    gemm2_kernel<<<(M + 127) / 128, 256, 0, stream>>>(AG, BA, V_in, V_out, W_self,
                                                      W_norel, d_out, M, flag);
}

// Round 4
// 325.165 us; speedup vs baseline: 1.0443x; 1.0443x over previous
//
#include <hip/hip_runtime.h>
#include <hip/hip_bf16.h>

#define D 128

typedef __bf16 bf16x8 __attribute__((ext_vector_type(8)));
typedef __bf16 bf16x4 __attribute__((ext_vector_type(4)));
typedef __bf16 bf16x2 __attribute__((ext_vector_type(2)));
typedef float  f32x4  __attribute__((ext_vector_type(4)));
typedef float  f32x2  __attribute__((ext_vector_type(2)));
typedef unsigned int u32x4 __attribute__((ext_vector_type(4)));

template <int ISBF>
__device__ __forceinline__ bf16x8 ld8(const void* p, size_t elem)
{
    if (ISBF) return *(const bf16x8*)((const __bf16*)p + elem);
    const f32x4* f = (const f32x4*)((const float*)p + elem);
    f32x4 lo = f[0], hi = f[1];
    bf16x8 r;
    r[0] = (__bf16)lo[0]; r[1] = (__bf16)lo[1]; r[2] = (__bf16)lo[2]; r[3] = (__bf16)lo[3];
    r[4] = (__bf16)hi[0]; r[5] = (__bf16)hi[1]; r[6] = (__bf16)hi[2]; r[7] = (__bf16)hi[3];
    return r;
}
template <int ISBF>
__device__ __forceinline__ float ldf(const void* p, size_t elem)
{
    return ISBF ? (float)((const __bf16*)p)[elem] : ((const float*)p)[elem];
}

// bf16 pair (packed in one u32) -> f32x2 via bit ops (no cvt chain)
__device__ __forceinline__ f32x2 bfpair(unsigned int u)
{
    f32x2 r;
    r[0] = __builtin_bit_cast(float, u << 16);
    r[1] = __builtin_bit_cast(float, u & 0xffff0000u);
    return r;
}

// packed f32 fma: d = a*b + c (VOP3P v_pk_fma_f32, gfx90a+)
__device__ __forceinline__ f32x2 pkfma(f32x2 a, f32x2 b, f32x2 c)
{
    f32x2 d;
    asm("v_pk_fma_f32 %0, %1, %2, %3" : "=v"(d) : "v"(a), "v"(b), "v"(c));
    return d;
}

// ---------------------------------------------------------------------------
// hist + fused dtype probe (block 0): 1 = bf16-packed, 0 = fp32.
// ---------------------------------------------------------------------------
__global__ __launch_bounds__(256) void hist_detect_kernel(
    const int* __restrict__ tgt, int* __restrict__ counts, int E,
    const unsigned int* __restrict__ w, int* __restrict__ flag)
{
    __shared__ int cnt[256];
    int e = blockIdx.x * 256 + threadIdx.x;
    if (e < E) atomicAdd(&counts[tgt[e]], 1);
    if (blockIdx.x == 0) {
        int c = 0;
#pragma unroll
        for (int i = 0; i < 4; ++i) {
            unsigned int v = w[threadIdx.x * 4 + i];
            unsigned int ex = (v >> 7) & 0xFF;
            if (ex >= 90 && ex <= 134) ++c;
        }
        cnt[threadIdx.x] = c;
        __syncthreads();
        for (int s = 128; s > 0; s >>= 1) {
            if (threadIdx.x < s) cnt[threadIdx.x] += cnt[threadIdx.x + s];
            __syncthreads();
        }
        if (threadIdx.x == 0) flag[0] = (cnt[0] > 614) ? 1 : 0;
    }
}

// ---------------------------------------------------------------------------
// Gate pre-activations G[t][n] (16 lanes/node) + fused bias-table build
// (first 101 blocks): Bz[101][128] bf16 (0..49=b_in, 50..99=b_out, 100=0),
// Bgz[101] f32 gate biases.
// ---------------------------------------------------------------------------
template <int ISBF>
__device__ __forceinline__ void gate_bias_body(
    const void* __restrict__ A,
    const void* __restrict__ g0, const void* __restrict__ g1,
    const void* __restrict__ g2, const void* __restrict__ g3,
    const void* __restrict__ b_in, const void* __restrict__ b_out,
    const void* __restrict__ bg_in, const void* __restrict__ bg_out,
    float* __restrict__ G, __bf16* __restrict__ Bz, float* __restrict__ Bgz,
    int M)
{
    // --- bias table part (independent of gate part) ---
    if (blockIdx.x < 101 && threadIdx.x < 128) {
        int row = blockIdx.x;
        int tid = threadIdx.x;
        float v = 0.f, gv = 0.f;
        if (row < 50) {
            v  = ldf<ISBF>(b_in, (size_t)row * D + tid);
            gv = ldf<ISBF>(bg_in, row);
        } else if (row < 100) {
            int rr = row - 50;
            v  = ldf<ISBF>(b_out, (size_t)rr * D + tid);
            gv = ldf<ISBF>(bg_out, rr);
        }
        Bz[(size_t)row * D + tid] = (__bf16)v;
        if (tid == 0) Bgz[row] = gv;
    }

    // --- gate part ---
    int node = blockIdx.x * 16 + (threadIdx.x >> 4);
    if (node >= M) return;
    int lane16 = threadIdx.x & 15;
    int dd = lane16 * 8;
    bf16x8 a  = ld8<ISBF>(A, (size_t)node * D + dd);
    bf16x8 q0 = ld8<ISBF>(g0, dd);
    bf16x8 q1 = ld8<ISBF>(g1, dd);
    bf16x8 q2 = ld8<ISBF>(g2, dd);
    bf16x8 q3 = ld8<ISBF>(g3, dd);
    float s0 = 0.f, s1 = 0.f, s2 = 0.f, s3 = 0.f;
#pragma unroll
    for (int k = 0; k < 8; ++k) {
        float af = (float)a[k];
        s0 = fmaf(af, (float)q0[k], s0);
        s1 = fmaf(af, (float)q1[k], s1);
        s2 = fmaf(af, (float)q2[k], s2);
        s3 = fmaf(af, (float)q3[k], s3);
    }
#pragma unroll
    for (int off = 8; off > 0; off >>= 1) {
        s0 += __shfl_xor(s0, off);
        s1 += __shfl_xor(s1, off);
        s2 += __shfl_xor(s2, off);
        s3 += __shfl_xor(s3, off);
    }
    if (lane16 == 0) {
        G[(size_t)0 * M + node] = s0;
        G[(size_t)1 * M + node] = s1;
        G[(size_t)2 * M + node] = s2;
        G[(size_t)3 * M + node] = s3;
    }
}

__global__ __launch_bounds__(256) void gate_bias_kernel(
    const void* __restrict__ A,
    const void* __restrict__ g0, const void* __restrict__ g1,
    const void* __restrict__ g2, const void* __restrict__ g3,
    const void* __restrict__ b_in, const void* __restrict__ b_out,
    const void* __restrict__ bg_in, const void* __restrict__ bg_out,
    float* __restrict__ G, __bf16* __restrict__ Bz, float* __restrict__ Bgz,
    int M, const int* __restrict__ flag)
{
    if (flag[0]) gate_bias_body<1>(A, g0, g1, g2, g3, b_in, b_out, bg_in, bg_out, G, Bz, Bgz, M);
    else         gate_bias_body<0>(A, g0, g1, g2, g3, b_in, b_out, bg_in, bg_out, G, Bz, Bgz, M);
}

// ---------------------------------------------------------------------------
// CSR build (verified R4-R6); scan2 inlined into scan3.
// ---------------------------------------------------------------------------
__global__ __launch_bounds__(256) void scan1_kernel(
    const int* __restrict__ counts, int* __restrict__ rowptr,
    int* __restrict__ bsum, int M)
{
    __shared__ int sh[256];
    int base = blockIdx.x * 1024 + threadIdx.x * 4;
    int v[4];
#pragma unroll
    for (int k = 0; k < 4; ++k)
        v[k] = (base + k < M) ? counts[base + k] : 0;
    int tot = v[0] + v[1] + v[2] + v[3];
    sh[threadIdx.x] = tot;
    __syncthreads();
    for (int off = 1; off < 256; off <<= 1) {
        int t = (threadIdx.x >= off) ? sh[threadIdx.x - off] : 0;
        __syncthreads();
        sh[threadIdx.x] += t;
        __syncthreads();
    }
    int run = sh[threadIdx.x] - tot;
#pragma unroll
    for (int k = 0; k < 4; ++k) {
        if (base + k < M) rowptr[base + k] = run;
        run += v[k];
    }
    if (threadIdx.x == 255) bsum[blockIdx.x] = sh[255];
}

__global__ __launch_bounds__(256) void scan3_kernel(
    int* __restrict__ rowptr, int* __restrict__ cursor,
    const int* __restrict__ bsum, int M, int E)
{
    int b = blockIdx.x;
    int o = 0;
    for (int i = 0; i < b; ++i) o += bsum[i];   // uniform, NB<=98, L2-hot
    int base = b * 1024 + threadIdx.x * 4;
#pragma unroll
    for (int k = 0; k < 4; ++k) {
        int i = base + k;
        if (i < M) {
            int r = rowptr[i] + o;
            rowptr[i] = r;
            cursor[i] = r;
        }
    }
    if (b == 0 && threadIdx.x == 0) rowptr[M] = E;
}

__global__ __launch_bounds__(256) void scatter_kernel(
    const int* __restrict__ deprel, const int* __restrict__ deparc,
    const int* __restrict__ src, const int* __restrict__ tgt,
    int* __restrict__ cursor, int2* __restrict__ recs, int E)
{
    int e = blockIdx.x * 256 + threadIdx.x;
    if (e >= E) return;
    int g = tgt[e];
    int pos = atomicAdd(&cursor[g], 1);
    recs[pos] = make_int2(src[e], (deprel[e] << 2) | deparc[e]);
}

// ---------------------------------------------------------------------------
// Phase A v4: 16 lanes/node, natural node order (R2 locality), 3-deep
// pipeline, packed-f32 FMA, branchless bias table, NON-TEMPORAL AG/BA
// stores (keep L2 for the inp gather).
// ---------------------------------------------------------------------------
template <int ISBF>
__device__ __forceinline__ void edge_agg_body(
    const void* __restrict__ inp, const float* __restrict__ G,
    const __bf16* __restrict__ Bz, const float* __restrict__ Bgz,
    const int* __restrict__ rowptr, const int2* __restrict__ recs,
    __bf16* __restrict__ AG, __bf16* __restrict__ BA, int M)
{
    const int g = blockIdx.x * 16 + (threadIdx.x >> 4);
    if (g >= M) return;
    const int lane16 = threadIdx.x & 15;
    const int dd = lane16 * 8;

    const int beg = rowptr[g], end = rowptr[g + 1];
    const int n = end - beg;

    f32x2 a0[4], a1[4], a2[4], a3[4], ba[4];
#pragma unroll
    for (int k = 0; k < 4; ++k) {
        a0[k] = (f32x2){0.f, 0.f}; a1[k] = (f32x2){0.f, 0.f};
        a2[k] = (f32x2){0.f, 0.f}; a3[k] = (f32x2){0.f, 0.f};
        ba[k] = (f32x2){0.f, 0.f};
    }

    // pipeline stages
    bf16x8 v0 = {}, bz0 = {}, v1 = {}, bz1 = {};
    float gp0 = 0.f, bg0 = 0.f, gp1 = 0.f, bg1 = 0.f;
    int t0 = 0, t1 = 0;
    int2 r2 = make_int2(0, 0);

    auto issue = [&](int2 rec, bf16x8& v, bf16x8& bz, float& gp, float& bg, int& t) {
        t = rec.y & 3;
        int r = rec.y >> 2;
        int bidx = (t < 2) ? t * 50 + r : 100;
        gp = G[(size_t)t * M + rec.x];
        bg = Bgz[bidx];
        v  = ld8<ISBF>(inp, (size_t)rec.x * D + dd);
        bz = *(const bf16x8*)(Bz + (size_t)bidx * D + dd);
    };

    if (n > 0) issue(recs[beg], v0, bz0, gp0, bg0, t0);
    if (n > 1) issue(recs[beg + 1], v1, bz1, gp1, bg1, t1);
    if (n > 2) r2 = recs[beg + 2];

    for (int e = 0; e < n; ++e) {
        const bf16x8 v = v0, bz = bz0;
        const float gp = gp0, bg = bg0;
        const int t = t0;

        // shift + issue next
        v0 = v1; bz0 = bz1; gp0 = gp1; bg0 = bg1; t0 = t1;
        if (e + 2 < n) {
            issue(r2, v1, bz1, gp1, bg1, t1);
            if (e + 3 < n) r2 = recs[beg + e + 3];
        }

        const float gate = 1.f / (1.f + __expf(-(gp + bg)));
        const float w0s = (t == 0) ? gate : 0.f;
        const float w1s = (t == 1) ? gate : 0.f;
        const float w2s = (t == 2) ? gate : 0.f;
        const float w3s = (t == 3) ? gate : 0.f;
        const f32x2 w0 = {w0s, w0s}, w1 = {w1s, w1s};
        const f32x2 w2 = {w2s, w2s}, w3 = {w3s, w3s};
        const f32x2 gg = {gate, gate};

        const u32x4 uv = __builtin_bit_cast(u32x4, v);
        const u32x4 ub = __builtin_bit_cast(u32x4, bz);
#pragma unroll
        for (int k = 0; k < 4; ++k) {
            const f32x2 vf = bfpair(uv[k]);
            const f32x2 bf = bfpair(ub[k]);
            a0[k] = pkfma(vf, w0, a0[k]);
            a1[k] = pkfma(vf, w1, a1[k]);
            a2[k] = pkfma(vf, w2, a2[k]);
            a3[k] = pkfma(vf, w3, a3[k]);
            ba[k] = pkfma(bf, gg, ba[k]);
        }
    }

    // epilogue: non-temporal stores (streamed, no reuse in this kernel)
    __bf16* agrow = AG + (size_t)g * (4 * D);
    bf16x8 w;
#pragma unroll
    for (int k = 0; k < 4; ++k) { w[2*k] = (__bf16)a0[k][0]; w[2*k+1] = (__bf16)a0[k][1]; }
    __builtin_nontemporal_store(w, (bf16x8*)(agrow + 0 * D + dd));
#pragma unroll
    for (int k = 0; k < 4; ++k) { w[2*k] = (__bf16)a1[k][0]; w[2*k+1] = (__bf16)a1[k][1]; }
    __builtin_nontemporal_store(w, (bf16x8*)(agrow + 1 * D + dd));
#pragma unroll
    for (int k = 0; k < 4; ++k) { w[2*k] = (__bf16)a2[k][0]; w[2*k+1] = (__bf16)a2[k][1]; }
    __builtin_nontemporal_store(w, (bf16x8*)(agrow + 2 * D + dd));
#pragma unroll
    for (int k = 0; k < 4; ++k) { w[2*k] = (__bf16)a3[k][0]; w[2*k+1] = (__bf16)a3[k][1]; }
    __builtin_nontemporal_store(w, (bf16x8*)(agrow + 3 * D + dd));
#pragma unroll
    for (int k = 0; k < 4; ++k) { w[2*k] = (__bf16)ba[k][0]; w[2*k+1] = (__bf16)ba[k][1]; }
    __builtin_nontemporal_store(w, (bf16x8*)(BA + (size_t)g * D + dd));
}

__global__ __launch_bounds__(256) void edge_agg_kernel(
    const void* __restrict__ inp, const float* __restrict__ G,
    const __bf16* __restrict__ Bz, const float* __restrict__ Bgz,
    const int* __restrict__ rowptr, const int2* __restrict__ recs,
    __bf16* __restrict__ AG, __bf16* __restrict__ BA, int M,
    const int* __restrict__ flag)
{
    if (flag[0]) edge_agg_body<1>(inp, G, Bz, Bgz, rowptr, recs, AG, BA, M);
    else         edge_agg_body<0>(inp, G, Bz, Bgz, rowptr, recs, AG, BA, M);
}

// ---------------------------------------------------------------------------
// Phase B: out = AG[M,512] @ WW^T + BA, W staged in LDS (XOR-swizzled).
// AG/BA reads and out stores are non-temporal (single-use streams).
// ---------------------------------------------------------------------------
template <int ISBF>
__device__ __forceinline__ void gemm2_body(
    const __bf16* __restrict__ AG, const __bf16* __restrict__ BA,
    const void* __restrict__ W0, const void* __restrict__ W1,
    const void* __restrict__ W2, const void* __restrict__ W3,
    void* __restrict__ out, int M)
{
    __shared__ __bf16 Wsh[128 * 128];   // 32 KB, row f: 16 slots of 16B, swizzled

    const int wave = threadIdx.x >> 6;
    const int lane = threadIdx.x & 63;
    const int lrow = lane & 15;
    const int kgrp = lane >> 4;
    const int m_base = blockIdx.x * 128 + wave * 32;

    int n0 = m_base + lrow;      if (n0 >= M) n0 = 0;   // clamped; stores guarded
    int n1 = m_base + 16 + lrow; if (n1 >= M) n1 = 0;

    const void* Ws[4] = {W0, W1, W2, W3};

    f32x4 acc[2][8];
#pragma unroll
    for (int i = 0; i < 2; ++i)
#pragma unroll
        for (int j = 0; j < 8; ++j)
            acc[i][j] = (f32x4){0.f, 0.f, 0.f, 0.f};

    for (int t = 0; t < 4; ++t) {
        const void* W = Ws[t];
#pragma unroll
        for (int i = 0; i < 8; ++i) {
            int slot = threadIdx.x + 256 * i;
            int f = slot >> 4;
            int s = slot & 15;
            int sp = s ^ (f & 7);
            bf16x8 v = ld8<ISBF>(W, (size_t)f * D + s * 8);
            *(bf16x8*)(Wsh + f * 128 + sp * 8) = v;
        }
        __syncthreads();

#pragma unroll
        for (int ks = 0; ks < 4; ++ks) {
            const int k0 = ks * 32 + kgrp * 8;                 // k within t
            bf16x8 af0 = __builtin_nontemporal_load(
                (const bf16x8*)(AG + (size_t)n0 * (4 * D) + t * D + k0));
            bf16x8 af1 = __builtin_nontemporal_load(
                (const bf16x8*)(AG + (size_t)n1 * (4 * D) + t * D + k0));
            const int slot = 4 * ks + kgrp;                    // 16B slot index
#pragma unroll
            for (int ft = 0; ft < 8; ++ft) {
                int f = ft * 16 + lrow;
                int sp = slot ^ (f & 7);
                bf16x8 wf = *(const bf16x8*)(Wsh + f * 128 + sp * 8);
                acc[0][ft] = __builtin_amdgcn_mfma_f32_16x16x32_bf16(wf, af0, acc[0][ft], 0, 0, 0);
                acc[1][ft] = __builtin_amdgcn_mfma_f32_16x16x32_bf16(wf, af1, acc[1][ft], 0, 0, 0);
            }
        }
        __syncthreads();
    }

    // epilogue (layout verified R5/R6): node = col, features = kgrp*4+reg +ft*16
#pragma unroll
    for (int nt = 0; nt < 2; ++nt) {
        int node = m_base + nt * 16 + lrow;
        if (node < M) {
#pragma unroll
            for (int ft = 0; ft < 8; ++ft) {
                int f0 = ft * 16 + kgrp * 4;
                bf16x4 bb = __builtin_nontemporal_load(
                    (const bf16x4*)(BA + (size_t)node * D + f0));
                f32x4 v = acc[nt][ft];
                v[0] += (float)bb[0]; v[1] += (float)bb[1];
                v[2] += (float)bb[2]; v[3] += (float)bb[3];
                if (ISBF) {
                    bf16x4 w4;
                    w4[0] = (__bf16)v[0]; w4[1] = (__bf16)v[1];
                    w4[2] = (__bf16)v[2]; w4[3] = (__bf16)v[3];
                    __builtin_nontemporal_store(w4,
                        (bf16x4*)((__bf16*)out + (size_t)node * D + f0));
                } else {
                    __builtin_nontemporal_store(v,
                        (f32x4*)((float*)out + (size_t)node * D + f0));
                }
            }
        }
    }
}

__global__ __launch_bounds__(256) void gemm2_kernel(
    const __bf16* __restrict__ AG, const __bf16* __restrict__ BA,
    const void* __restrict__ W0, const void* __restrict__ W1,
    const void* __restrict__ W2, const void* __restrict__ W3,
    void* __restrict__ out, int M, const int* __restrict__ flag)
{
    if (flag[0]) gemm2_body<1>(AG, BA, W0, W1, W2, W3, out, M);
    else         gemm2_body<0>(AG, BA, W0, W1, W2, W3, out, M);
}

__global__ void sentinel_kernel(__bf16* o, int n)
{
    int i = blockIdx.x * blockDim.x + threadIdx.x;
    if (i < n) o[i] = (__bf16)12345.0f;
}

static inline size_t align256(size_t x) { return (x + 255) & ~(size_t)255; }

extern "C" void kernel_launch(void* const* d_in, const int* in_sizes, int n_in,
                              void* d_out, int out_size, void* d_ws, size_t ws_size,
                              hipStream_t stream)
{
    const void* inp       = d_in[0];
    const int*  deprel    = (const int*)d_in[1];
    const int*  deparc    = (const int*)d_in[2];
    const int*  eidx      = (const int*)d_in[3];
    const void* V_in      = d_in[4];
    const void* b_in      = d_in[5];
    const void* V_in_g    = d_in[6];
    const void* b_in_g    = d_in[7];
    const void* V_out     = d_in[8];
    const void* b_out     = d_in[9];
    const void* V_out_g   = d_in[10];
    const void* b_out_g   = d_in[11];
    const void* W_self    = d_in[12];
    const void* W_self_g  = d_in[13];
    const void* W_norel   = d_in[14];
    const void* W_norel_g = d_in[15];

    const int M = in_sizes[0] / D;   // 100000
    const int E = in_sizes[1];       // 600000
    const int* src = eidx;
    const int* tgt = eidx + E;
    const int NB = (M + 1023) / 1024;

    size_t off = 0;
    size_t o_flag   = off; off = align256(off + sizeof(int));
    size_t o_AG     = off; off = align256(off + (size_t)M * 4 * D * sizeof(__bf16));
    size_t o_BA     = off; off = align256(off + (size_t)M * D * sizeof(__bf16));
    size_t o_G      = off; off = align256(off + (size_t)4 * M * sizeof(float));
    size_t o_counts = off; off = align256(off + (size_t)M * sizeof(int));
    size_t o_rowptr = off; off = align256(off + (size_t)(M + 1) * sizeof(int));
    size_t o_cursor = off; off = align256(off + (size_t)M * sizeof(int));
    size_t o_bsum   = off; off = align256(off + (size_t)NB * sizeof(int));
    size_t o_recs   = off; off = align256(off + (size_t)E * sizeof(int2));
    size_t o_Bz     = off; off = align256(off + (size_t)101 * D * sizeof(__bf16));
    size_t o_Bgz    = off; off = align256(off + (size_t)101 * sizeof(float));

    if (off > ws_size) {
        sentinel_kernel<<<(out_size + 255) / 256, 256, 0, stream>>>(
            (__bf16*)d_out, out_size);
        return;
    }

    int*    flag   = (int*)((char*)d_ws + o_flag);
    __bf16* AG     = (__bf16*)((char*)d_ws + o_AG);
    __bf16* BA     = (__bf16*)((char*)d_ws + o_BA);
    float*  Gbuf   = (float*)((char*)d_ws + o_G);
    int*    counts = (int*)((char*)d_ws + o_counts);
    int*    rowptr = (int*)((char*)d_ws + o_rowptr);
    int*    cursor = (int*)((char*)d_ws + o_cursor);
    int*    bsum   = (int*)((char*)d_ws + o_bsum);
    int2*   recs   = (int2*)((char*)d_ws + o_recs);
    __bf16* Bz     = (__bf16*)((char*)d_ws + o_Bz);
    float*  Bgz    = (float*)((char*)d_ws + o_Bgz);

    // CSR build (detect fused into hist block 0)
    hipMemsetAsync(counts, 0, (size_t)M * sizeof(int), stream);
    hist_detect_kernel<<<(E + 255) / 256, 256, 0, stream>>>(
        tgt, counts, E, (const unsigned int*)inp, flag);
    scan1_kernel<<<NB, 256, 0, stream>>>(counts, rowptr, bsum, M);
    scan3_kernel<<<NB, 256, 0, stream>>>(rowptr, cursor, bsum, M, E);
    scatter_kernel<<<(E + 255) / 256, 256, 0, stream>>>(deprel, deparc, src, tgt,
                                                        cursor, recs, E);

    // gates + bias tables (fused)
    gate_bias_kernel<<<(M + 15) / 16, 256, 0, stream>>>(
        inp, V_in_g, V_out_g, W_self_g, W_norel_g,
        b_in, b_out, b_in_g, b_out_g, Gbuf, Bz, Bgz, M, flag);

    // aggregate-then-transform
    edge_agg_kernel<<<(M + 15) / 16, 256, 0, stream>>>(inp, Gbuf, Bz, Bgz,
                                                       rowptr, recs, AG, BA, M, flag);
    gemm2_kernel<<<(M + 127) / 128, 256, 0, stream>>>(AG, BA, V_in, V_out, W_self,
                                                      W_norel, d_out, M, flag);
}